// Round 10
// baseline (390.409 us; speedup 1.0000x reference)
//
#include <hip/hip_runtime.h>
#include <hip/hip_bf16.h>

typedef __hip_bfloat16 bf16;
typedef unsigned short u16;
typedef short bf16x8 __attribute__((ext_vector_type(8)));
typedef float f32x4  __attribute__((ext_vector_type(4)));

// problem constants (fixed instance)
#define BB    2
#define LL    6
#define NWIN  64     // X*Y
#define PP    49     // w1*w2
#define DIMM  256
#define HEADS 8
#define CHN   32
#define SS    294    // LL*PP
#define ASTRIDE 264  // LDS A-tile row stride in u16
#define BSTRIDE 304  // biasM row stride (f32)
#define VSTRIDE 296  // vT row stride u16 (148 words = 20 mod 32 -> 2-way free, same class as 168)
#define PSTRIDE 168  // strip row stride u16 (84 words = 20 mod 32; R5-proven)

__device__ __forceinline__ u16 bfbits(float x) { return __bfloat16_as_ushort(__float2bfloat16(x)); }
__device__ __forceinline__ f32x4 mfma16(bf16x8 a, bf16x8 b, f32x4 c) {
    return __builtin_amdgcn_mfma_f32_16x16x32_bf16(a, b, c, 0, 0, 0);
}

// ---------------- merged prep kernel ----------------
__global__ __launch_bounds__(256) void k_prep(
    const float* __restrict__ Wq, const float* __restrict__ Wk, const float* __restrict__ Wv,
    const float* __restrict__ Wo, const float* __restrict__ ra, const float* __restrict__ rm,
    const float* __restrict__ bt,
    u16* __restrict__ wT, u16* __restrict__ Wob, u16* __restrict__ raT, u16* __restrict__ rmb,
    float* __restrict__ biasM)
{
    const int blk = blockIdx.x;
    if (blk < 1792) {
        const int idx = blk*256 + threadIdx.x;
        if (idx >= 7*65536) return;
        const int mat = idx >> 16, rem = idx & 65535;
        if (mat < 6) {
            const int tz = mat >> 1, t = mat & 1;
            const int e = rem >> 8, d = rem & 255;
            const float* W = (tz == 0 ? Wq : tz == 1 ? Wk : Wv);
            wT[mat*65536 + rem] = bfbits(W[t*65536 + d*256 + e]);
        } else {
            Wob[rem] = bfbits(Wo[rem]);
        }
    } else if (blk < 1920) {
        const int idx = (blk - 1792)*256 + threadIdx.x;
        if (idx < 4*HEADS*CHN*CHN) {
            const int pm = idx >> 10, cf = idx & 1023, c = cf >> 5, f = cf & 31;
            raT[(pm << 10) + (f << 5) + c] = bfbits(ra[idx]);   // [pair][m][f][c]
            rmb[idx] = bfbits(rm[idx]);                          // [pair][m][c][f]
        }
    } else {
        const int idx = (blk - 1920)*256 + threadIdx.x;
        if (idx < HEADS*SS*BSTRIDE) {
            const int m = idx / (SS*BSTRIDE);
            const int rem = idx % (SS*BSTRIDE);
            const int s1 = rem / BSTRIDE, s2 = rem % BSTRIDE;
            float val = 0.f;
            if (s2 < SS) {
                const int i1 = s1/49, p1 = s1 - i1*49, h1 = p1/7, w1 = p1 - h1*7;
                const int j2 = s2/49, p2 = s2 - j2*49, h2 = p2/7, w2 = p2 - h2*7;
                const int rc = i1*169 + h1*13 + w1, cc = j2*169 + h2*13 + w2;
                val = bt[(rc - cc + 929)*8 + m];
            }
            biasM[idx] = val;
        }
    }
}

// ---------------- kernel 1: QKV projection via MFMA ----------------
__global__ __launch_bounds__(256) void k_qkv2(
    const float* __restrict__ x, const u16* __restrict__ wT,
    const float* __restrict__ bq, const float* __restrict__ bk, const float* __restrict__ bv,
    const int* __restrict__ atype,
    u16* __restrict__ q, u16* __restrict__ k, u16* __restrict__ v)
{
    __shared__ __align__(16) u16 As[64*ASTRIDE]; // 33792 B
    const int tid = threadIdx.x;
    const int w = tid >> 6, lane = tid & 63;
    const int g4 = lane >> 4, c16 = lane & 15;
    const int bid = blockIdx.x;              // (b*6+l)*64+n
    const int nwin = bid & 63;
    const int l = (bid >> 6) % LL;
    const int b = bid / (LL*NWIN);

    const float4* xp = (const float4*)(x + (size_t)bid * (PP*DIMM));
    for (int idx = tid; idx < 49*64; idx += 256) {
        const int row = idx >> 6, c4 = idx & 63;
        const float4 xv = xp[idx];
        ushort4 h;
        h.x = bfbits(xv.x); h.y = bfbits(xv.y); h.z = bfbits(xv.z); h.w = bfbits(xv.w);
        *(ushort4*)&As[row*ASTRIDE + c4*4] = h;
    }
    const ushort4 z4 = {0, 0, 0, 0};
    for (int idx = tid; idx < 15*66; idx += 256) {
        const int row = 49 + idx/66, c4 = idx%66;
        *(ushort4*)&As[row*ASTRIDE + c4*4] = z4;
    }
    __syncthreads();

    const int t = (l == 0) ? 0 : atype[0];
    const f32x4 zero4 = {0.f, 0.f, 0.f, 0.f};

    for (int tz = 0; tz < 3; ++tz) {
        const u16* WT = wT + (size_t)(tz*2 + t)*65536;
        const float* bias = (tz == 0 ? bq : tz == 1 ? bk : bv) + t*DIMM;
        u16* dst = (tz == 0 ? q : tz == 1 ? k : v);
        const float scale = (tz == 0) ? 0.17677669529663687f : 1.0f;

        f32x4 acc[4][4];
        #pragma unroll
        for (int mm = 0; mm < 4; ++mm)
            #pragma unroll
            for (int nn = 0; nn < 4; ++nn) acc[mm][nn] = zero4;

        for (int ks = 0; ks < 8; ++ks) {
            bf16x8 a[4], bb[4];
            #pragma unroll
            for (int mm = 0; mm < 4; ++mm)
                a[mm] = *(const bf16x8*)&As[(mm*16 + c16)*ASTRIDE + ks*32 + g4*8];
            #pragma unroll
            for (int nn = 0; nn < 4; ++nn)
                bb[nn] = *(const bf16x8*)&WT[(size_t)(w*64 + nn*16 + c16)*256 + ks*32 + g4*8];
            #pragma unroll
            for (int mm = 0; mm < 4; ++mm)
                #pragma unroll
                for (int nn = 0; nn < 4; ++nn)
                    acc[mm][nn] = mfma16(a[mm], bb[nn], acc[mm][nn]);
        }

        #pragma unroll
        for (int nn = 0; nn < 4; ++nn) {
            const int col = w*64 + nn*16 + c16;
            const float bval = bias[col];
            const int head = col >> 5, c = col & 31;
            const size_t base = (((size_t)(b*NWIN + nwin)*HEADS + head)*SS + l*PP)*CHN + c;
            #pragma unroll
            for (int mm = 0; mm < 4; ++mm) {
                #pragma unroll
                for (int r = 0; r < 4; ++r) {
                    const int row = mm*16 + g4*4 + r;
                    if (row < PP)
                        dst[base + (size_t)row*CHN] = bfbits((acc[mm][nn][r] + bval)*scale);
                }
            }
        }
    }
}

// ---------------- kernel 2: MFMA hetero attention per (b,n,m) ----------------
// Two-pass score recompute (pass1 max-only, pass2 exp+sum+store) with deferred
// normalization -> acc[19] eliminated, target VGPR <= 128 (4 waves/SIMD).
// LDS: vT 32*296+48 = 19040 B + wbuf 4*16*168*2 = 21504 B -> 40544 B -> 4 blocks/CU.
// NOTE: no __launch_bounds__ min-waves (R4/R7: 230 MB spills).
// NOTE: online-softmax *split* (R6-R8) is 2.4x slower - this is NOT that: single
// global max, softmax math identical to R5, only score recompute + late normalize.
__global__ __launch_bounds__(256) void k_attn(
    const u16* __restrict__ q, const u16* __restrict__ kk_, const u16* __restrict__ v,
    const u16* __restrict__ raT, const u16* __restrict__ rmb,
    const float* __restrict__ biasM, const int* __restrict__ atype,
    u16* __restrict__ o_pre)
{
    __shared__ __align__(16) u16 vT[32*VSTRIDE + 48];
    __shared__ __align__(16) u16 wbuf[4*16*PSTRIDE];

    const int tid  = threadIdx.x;
    const int w    = tid >> 6;
    const int lane = tid & 63;
    const int g4   = lane >> 4;
    const int c16  = lane & 15;
    const int bid  = blockIdx.x;       // (b*64+n)*8+m
    const int m    = bid & 7;
    const int nwin = (bid >> 3) & 63;
    const int b    = bid >> 9;
    const int at   = atype[0];

    const size_t slab = (size_t)bid * (SS*CHN);
    const u16* qs  = q   + slab;
    const u16* ksg = kk_ + slab;
    const u16* vsg = v   + slab;
    const float* bm = biasM + (size_t)m*(SS*BSTRIDE);

    u16* wb = wbuf + w*(16*PSTRIDE);

    // ---- zero the true uninit holes (R6 lesson: only FINITE data is maskable):
    // cols 294,295 of each row (read by PV ks=9 with P=0) + 48-elem tail (row 31
    // col>=296 overrun). Cols 296.. of rows<31 alias the next row's v-data: finite, P=0. ----
    for (int idx = tid; idx < 112; idx += 256) {
        if (idx < 64) vT[(idx >> 1)*VSTRIDE + 294 + (idx & 1)] = 0;
        else          vT[32*VSTRIDE + (idx - 64)] = 0;
    }
    // ---- stage vT (transpose) ----
    for (int idx = tid; idx < SS*CHN/2; idx += 256) {
        const int s2 = idx >> 4;
        const int f2 = (idx & 15) << 1;
        const unsigned int val = *(const unsigned int*)(vsg + s2*CHN + f2);
        vT[f2*VSTRIDE + s2]     = (u16)(val & 0xffff);
        vT[(f2+1)*VSTRIDE + s2] = (u16)(val >> 16);
    }
    __syncthreads();

    const f32x4 zero4 = {0.f, 0.f, 0.f, 0.f};
    const bf16x8 zero8 = {0, 0, 0, 0, 0, 0, 0, 0};

    for (int job = w; job < 20; job += 4) {
        const int tile = (job == 19) ? 3 : job;
        const int tiv  = (job <= 3) ? 0 : at;
        const int pair0 = tiv*2;
        const int pair1 = tiv*2 + at;

        // ---- phase A: qw build (wb as [16][72]) ----
        const int rowA = tile*16 + c16;
        const bf16x8 aq = *(const bf16x8*)(qs + rowA*CHN + g4*8);
        {
            const u16* base0 = raT + (pair0*HEADS + m)*1024;
            const u16* base1 = raT + (pair1*HEADS + m)*1024;
            const bf16x8 b00 = *(const bf16x8*)(base0 + (c16     )*32 + g4*8);
            const bf16x8 b01 = *(const bf16x8*)(base0 + (16 + c16)*32 + g4*8);
            const bf16x8 b10 = *(const bf16x8*)(base1 + (c16     )*32 + g4*8);
            const bf16x8 b11 = *(const bf16x8*)(base1 + (16 + c16)*32 + g4*8);
            const f32x4 cqw00 = mfma16(aq, b00, zero4);
            const f32x4 cqw01 = mfma16(aq, b01, zero4);
            const f32x4 cqw10 = mfma16(aq, b10, zero4);
            const f32x4 cqw11 = mfma16(aq, b11, zero4);
            #pragma unroll
            for (int r = 0; r < 4; ++r) {
                const int row = g4*4 + r;
                wb[row*72 +      c16] = bfbits(cqw00[r]);
                wb[row*72 + 16 + c16] = bfbits(cqw01[r]);
                wb[row*72 + 32 + c16] = bfbits(cqw10[r]);
                wb[row*72 + 48 + c16] = bfbits(cqw11[r]);
            }
        }
        const bf16x8 A0 = *(const bf16x8*)(wb + c16*72 +      g4*8);
        const bf16x8 A1 = *(const bf16x8*)(wb + c16*72 + 32 + g4*8);

        int boff[4];
        #pragma unroll
        for (int r = 0; r < 4; ++r) {
            const int s1r = tile*16 + g4*4 + r;
            const int s1c = (s1r < SS) ? s1r : 293;
            boff[r] = s1c*BSTRIDE;
        }

        // ---- pass 1: scores -> running max only (4-reg window, no acc array) ----
        float mx[4];
        #pragma unroll
        for (int r = 0; r < 4; ++r) mx[r] = -1e30f;
        #pragma unroll
        for (int t = 0; t < 19; ++t) {
            const bf16x8 bk = *(const bf16x8*)(ksg + (t*16 + c16)*CHN + g4*8);
            f32x4 s;
            if (t < 3)       s = mfma16(A0, bk, zero4);
            else if (t == 3) {
                const f32x4 cA = mfma16(A0, bk, zero4);
                const f32x4 cB = mfma16(A1, bk, zero4);
                #pragma unroll
                for (int r = 0; r < 4; ++r) s[r] = (c16 == 0) ? cA[r] : cB[r];
            }
            else             s = mfma16(A1, bk, zero4);
            #pragma unroll
            for (int r = 0; r < 4; ++r) {
                float v = s[r] + bm[boff[r] + t*16 + c16];
                if (t == 18) v = (c16 < 6) ? v : -1e30f;
                mx[r] = fmaxf(mx[r], v);
            }
        }
        #pragma unroll
        for (int off = 1; off < 16; off <<= 1)
            #pragma unroll
            for (int r = 0; r < 4; ++r) mx[r] = fmaxf(mx[r], __shfl_xor(mx[r], off));

        float sm[4];
        #pragma unroll
        for (int r = 0; r < 4; ++r) sm[r] = 0.f;

        // ---- pass 2a: recompute tiles 0..9, exp + sum + store UNNORMALIZED P ----
        #pragma unroll
        for (int t = 0; t < 10; ++t) {
            const bf16x8 bk = *(const bf16x8*)(ksg + (t*16 + c16)*CHN + g4*8);
            f32x4 s;
            if (t < 3)       s = mfma16(A0, bk, zero4);
            else if (t == 3) {
                const f32x4 cA = mfma16(A0, bk, zero4);
                const f32x4 cB = mfma16(A1, bk, zero4);
                #pragma unroll
                for (int r = 0; r < 4; ++r) s[r] = (c16 == 0) ? cA[r] : cB[r];
            }
            else             s = mfma16(A1, bk, zero4);
            #pragma unroll
            for (int r = 0; r < 4; ++r) {
                const float e = __expf(s[r] + bm[boff[r] + t*16 + c16] - mx[r]);
                sm[r] += e;
                wb[(g4*4 + r)*PSTRIDE + t*16 + c16] = bfbits(e);
            }
        }

        // ---- PV pass 1: ks 0..4 ----
        f32x4 aggF0a = zero4, aggF0b = zero4, aggF1a = zero4, aggF1b = zero4;
        f32x4 agg00 = zero4, agg01 = zero4;
        bf16x8 asave0, asave1;
        #pragma unroll
        for (int ks = 0; ks < 5; ++ks) {
            const bf16x8 ap  = *(const bf16x8*)(wb + c16*PSTRIDE + ks*32 + g4*8);
            const bf16x8 bv0 = *(const bf16x8*)(vT + (c16     )*VSTRIDE + ks*32 + g4*8);
            const bf16x8 bv1 = *(const bf16x8*)(vT + (16 + c16)*VSTRIDE + ks*32 + g4*8);
            if (ks & 1) { aggF0b = mfma16(ap, bv0, aggF0b); aggF1b = mfma16(ap, bv1, aggF1b); }
            else        { aggF0a = mfma16(ap, bv0, aggF0a); aggF1a = mfma16(ap, bv1, aggF1a); }
            if (ks == 0) asave0 = ap;
            if (ks == 1) asave1 = ap;
        }
        // ---- j=0 partial: masked asave1 (keep s2<=48) x main vT (R7/R8-verified) ----
        {
            bf16x8 a1m;
            if (g4 < 2)       a1m = asave1;
            else if (g4 == 2) { a1m = zero8; a1m[0] = asave1[0]; }
            else              a1m = zero8;
            const bf16x8 b00 = *(const bf16x8*)(vT + (c16     )*VSTRIDE +      g4*8);
            const bf16x8 b01 = *(const bf16x8*)(vT + (16 + c16)*VSTRIDE +      g4*8);
            const bf16x8 b10 = *(const bf16x8*)(vT + (c16     )*VSTRIDE + 32 + g4*8);
            const bf16x8 b11 = *(const bf16x8*)(vT + (16 + c16)*VSTRIDE + 32 + g4*8);
            agg00 = mfma16(asave0, b00, agg00); agg00 = mfma16(a1m, b10, agg00);
            agg01 = mfma16(asave0, b01, agg01); agg01 = mfma16(a1m, b11, agg01);
        }

        // ---- pass 2b: recompute tiles 10..18 + zero pad tile ----
        #pragma unroll
        for (int t2 = 0; t2 < 9; ++t2) {
            const int t = 10 + t2;
            const bf16x8 bk = *(const bf16x8*)(ksg + (t*16 + c16)*CHN + g4*8);
            const f32x4 s = mfma16(A1, bk, zero4);
            #pragma unroll
            for (int r = 0; r < 4; ++r) {
                float e = __expf(s[r] + bm[boff[r] + t*16 + c16] - mx[r]);
                if (t2 == 8) e = (c16 < 6) ? e : 0.f;
                sm[r] += e;
                wb[(g4*4 + r)*PSTRIDE + t2*16 + c16] = bfbits(e);
            }
        }
        #pragma unroll
        for (int r = 0; r < 4; ++r)
            wb[(g4*4 + r)*PSTRIDE + 9*16 + c16] = 0;

        // ---- PV pass 2: ks 5..9 ----
        #pragma unroll
        for (int ks2 = 0; ks2 < 5; ++ks2) {
            const int ks = 5 + ks2;
            const bf16x8 ap  = *(const bf16x8*)(wb + c16*PSTRIDE + ks2*32 + g4*8);
            const bf16x8 bv0 = *(const bf16x8*)(vT + (c16     )*VSTRIDE + ks*32 + g4*8);
            const bf16x8 bv1 = *(const bf16x8*)(vT + (16 + c16)*VSTRIDE + ks*32 + g4*8);
            if (ks2 & 1) { aggF0b = mfma16(ap, bv0, aggF0b); aggF1b = mfma16(ap, bv1, aggF1b); }
            else         { aggF0a = mfma16(ap, bv0, aggF0a); aggF1a = mfma16(ap, bv1, aggF1a); }
        }

        // ---- reduce sums, deferred normalization ----
        #pragma unroll
        for (int off = 1; off < 16; off <<= 1)
            #pragma unroll
            for (int r = 0; r < 4; ++r) sm[r] += __shfl_xor(sm[r], off);

        f32x4 agg0s0, agg0s1, agg10, agg11;
        #pragma unroll
        for (int r = 0; r < 4; ++r) {
            const float inv = 1.0f / sm[r];
            const float f0 = (aggF0a[r] + aggF0b[r]);
            const float f1 = (aggF1a[r] + aggF1b[r]);
            agg0s0[r] = agg00[r]*inv;
            agg0s1[r] = agg01[r]*inv;
            agg10[r]  = (f0 - agg00[r])*inv;
            agg11[r]  = (f1 - agg01[r])*inv;
        }

        // ---- phase E: msg transform (wb as [16][72] again) ----
        #pragma unroll
        for (int r = 0; r < 4; ++r) {
            const int row = g4*4 + r;
            wb[row*72 +      c16] = bfbits(agg0s0[r]);
            wb[row*72 + 16 + c16] = bfbits(agg0s1[r]);
            wb[row*72 + 32 + c16] = bfbits(agg10[r]);
            wb[row*72 + 48 + c16] = bfbits(agg11[r]);
        }
        const bf16x8 aA0 = *(const bf16x8*)(wb + c16*72 +      g4*8);
        const bf16x8 aA1 = *(const bf16x8*)(wb + c16*72 + 32 + g4*8);
        const u16* mb0 = rmb + (pair0*HEADS + m)*1024;
        const u16* mb1 = rmb + (pair1*HEADS + m)*1024;
        const bf16x8 bm00 = *(const bf16x8*)(mb0 + (c16     )*32 + g4*8);
        const bf16x8 bm01 = *(const bf16x8*)(mb0 + (16 + c16)*32 + g4*8);
        const bf16x8 bm10 = *(const bf16x8*)(mb1 + (c16     )*32 + g4*8);
        const bf16x8 bm11 = *(const bf16x8*)(mb1 + (16 + c16)*32 + g4*8);
        f32x4 out0 = mfma16(aA0, bm00, zero4); out0 = mfma16(aA1, bm10, out0);
        f32x4 out1 = mfma16(aA0, bm01, zero4); out1 = mfma16(aA1, bm11, out1);

        // ---- store bf16 ----
        #pragma unroll
        for (int r = 0; r < 4; ++r) {
            const int s1row = tile*16 + g4*4 + r;
            bool valid = (s1row < SS);
            if (job == 3)  valid = valid && (s1row == 48);
            if (job == 19) valid = valid && (s1row >= 49);
            if (valid) {
                const int i = s1row / 49, p = s1row - i*49;
                const size_t rb = ((size_t)((b*LL + i)*NWIN + nwin)*PP + p)*DIMM + m*CHN;
                o_pre[rb + c16]      = bfbits(out0[r]);
                o_pre[rb + 16 + c16] = bfbits(out1[r]);
            }
        }
    }
}

// ---------------- kernel 3: out = o_pre @ Wo^T via MFMA ----------------
__global__ __launch_bounds__(256) void k_out2(
    const u16* __restrict__ pre, const u16* __restrict__ Wob,
    float* __restrict__ out)
{
    __shared__ __align__(16) u16 As[64*ASTRIDE];
    const int tid = threadIdx.x;
    const int w = tid >> 6, lane = tid & 63;
    const int g4 = lane >> 4, c16 = lane & 15;
    const int bid = blockIdx.x;

    const uint4* pp = (const uint4*)(pre + (size_t)bid * (PP*DIMM));
    for (int idx = tid; idx < 49*32; idx += 256) {
        const int row = idx >> 5, c8 = idx & 31;
        *(uint4*)&As[row*ASTRIDE + c8*8] = pp[idx];
    }
    const ushort4 z4 = {0, 0, 0, 0};
    for (int idx = tid; idx < 15*66; idx += 256) {
        const int row = 49 + idx/66, c4 = idx%66;
        *(ushort4*)&As[row*ASTRIDE + c4*4] = z4;
    }
    __syncthreads();

    const f32x4 zero4 = {0.f, 0.f, 0.f, 0.f};
    f32x4 acc[4][4];
    #pragma unroll
    for (int mm = 0; mm < 4; ++mm)
        #pragma unroll
        for (int nn = 0; nn < 4; ++nn) acc[mm][nn] = zero4;

    for (int ks = 0; ks < 8; ++ks) {
        bf16x8 a[4], bb[4];
        #pragma unroll
        for (int mm = 0; mm < 4; ++mm)
            a[mm] = *(const bf16x8*)&As[(mm*16 + c16)*ASTRIDE + ks*32 + g4*8];
        #pragma unroll
        for (int nn = 0; nn < 4; ++nn)
            bb[nn] = *(const bf16x8*)&Wob[(size_t)(w*64 + nn*16 + c16)*256 + ks*32 + g4*8];
        #pragma unroll
        for (int mm = 0; mm < 4; ++mm)
            #pragma unroll
            for (int nn = 0; nn < 4; ++nn)
                acc[mm][nn] = mfma16(a[mm], bb[nn], acc[mm][nn]);
    }

    float* op = out + (size_t)bid * (PP*DIMM);
    #pragma unroll
    for (int nn = 0; nn < 4; ++nn) {
        const int col = w*64 + nn*16 + c16;
        #pragma unroll
        for (int mm = 0; mm < 4; ++mm) {
            #pragma unroll
            for (int r = 0; r < 4; ++r) {
                const int row = mm*16 + g4*4 + r;
                if (row < PP) op[(size_t)row*DIMM + col] = acc[mm][nn][r];
            }
        }
    }
}

extern "C" void kernel_launch(void* const* d_in, const int* in_sizes, int n_in,
                              void* d_out, int out_size, void* d_ws, size_t ws_size,
                              hipStream_t stream)
{
    (void)in_sizes; (void)n_in; (void)out_size; (void)ws_size;
    const float* x        = (const float*)d_in[0];
    const float* Wq       = (const float*)d_in[1];
    const float* bq       = (const float*)d_in[2];
    const float* Wk       = (const float*)d_in[3];
    const float* bk       = (const float*)d_in[4];
    const float* Wv       = (const float*)d_in[5];
    const float* bv       = (const float*)d_in[6];
    const float* rel_att  = (const float*)d_in[7];
    const float* rel_msg  = (const float*)d_in[8];
    const float* bias_tab = (const float*)d_in[9];
    const float* Wo       = (const float*)d_in[10];
    const int*   atype    = (const int*)d_in[11];
    float* out = (float*)d_out;

    // workspace layout (bytes):
    //  wT    bf16: [0, 786432)
    //  Wob   bf16: [786432, 917504)
    //  raT   bf16: [917504, 983040)
    //  rmb   bf16: [983040, 1048576)
    //  biasM f32 : [1048576, 3908608)
    //  qb, kb, vb, o_preb bf16: 4 x 19267584  -> total 80,978,944 B
    char* ws = (char*)d_ws;
    u16* wT     = (u16*)ws;
    u16* Wob    = (u16*)(ws + 786432);
    u16* raT    = (u16*)(ws + 917504);
    u16* rmb    = (u16*)(ws + 983040);
    float* biasM= (float*)(ws + 1048576);
    u16* qb     = (u16*)(ws + 3908608);
    u16* kb     = (u16*)(ws + 3908608 + 1ull*19267584);
    u16* vb     = (u16*)(ws + 3908608 + 2ull*19267584);
    u16* o_preb = (u16*)(ws + 3908608 + 3ull*19267584);

    k_prep<<<4713, 256, 0, stream>>>(Wq, Wk, Wv, Wo, rel_att, rel_msg, bias_tab,
                                     wT, Wob, raT, rmb, biasM);
    k_qkv2<<<BB*LL*NWIN, 256, 0, stream>>>(x, wT, bq, bk, bv, atype, qb, kb, vb);
    k_attn<<<BB*NWIN*HEADS, 256, 0, stream>>>(qb, kb, vb, raT, rmb, biasM, atype, o_preb);
    k_out2<<<BB*LL*NWIN, 256, 0, stream>>>(o_preb, Wob, out);
}

// Round 11
// 223.945 us; speedup vs baseline: 1.7433x; 1.7433x over previous
//
#include <hip/hip_runtime.h>
#include <hip/hip_bf16.h>

typedef __hip_bfloat16 bf16;
typedef unsigned short u16;
typedef short bf16x8 __attribute__((ext_vector_type(8)));
typedef float f32x4  __attribute__((ext_vector_type(4)));

// problem constants (fixed instance)
#define BB    2
#define LL    6
#define NWIN  64     // X*Y
#define PP    49     // w1*w2
#define DIMM  256
#define HEADS 8
#define CHN   32
#define SS    294    // LL*PP
#define ASTRIDE 264  // LDS A-tile row stride in u16
#define BSTRIDE 304  // biasM row stride (f32)
// k_attn strides: R5-proven pair (134 us). R9 (164/308) and R10 experiments were slower
// despite lower SQ_LDS_BANK_CONFLICT - counters are not time; keep 328/168.
#define VST 328
#define PST 168

__device__ __forceinline__ u16 bfbits(float x) { return __bfloat16_as_ushort(__float2bfloat16(x)); }
__device__ __forceinline__ f32x4 mfma16(bf16x8 a, bf16x8 b, f32x4 c) {
    return __builtin_amdgcn_mfma_f32_16x16x32_bf16(a, b, c, 0, 0, 0);
}

// ---------------- merged prep kernel ----------------
__global__ __launch_bounds__(256) void k_prep(
    const float* __restrict__ Wq, const float* __restrict__ Wk, const float* __restrict__ Wv,
    const float* __restrict__ Wo, const float* __restrict__ ra, const float* __restrict__ rm,
    const float* __restrict__ bt,
    u16* __restrict__ wT, u16* __restrict__ Wob, u16* __restrict__ raT, u16* __restrict__ rmb,
    float* __restrict__ biasM)
{
    const int blk = blockIdx.x;
    if (blk < 1792) {
        const int idx = blk*256 + threadIdx.x;
        if (idx >= 7*65536) return;
        const int mat = idx >> 16, rem = idx & 65535;
        if (mat < 6) {
            const int tz = mat >> 1, t = mat & 1;
            const int e = rem >> 8, d = rem & 255;
            const float* W = (tz == 0 ? Wq : tz == 1 ? Wk : Wv);
            wT[mat*65536 + rem] = bfbits(W[t*65536 + d*256 + e]);
        } else {
            Wob[rem] = bfbits(Wo[rem]);
        }
    } else if (blk < 1920) {
        const int idx = (blk - 1792)*256 + threadIdx.x;
        if (idx < 4*HEADS*CHN*CHN) {
            const int pm = idx >> 10, cf = idx & 1023, c = cf >> 5, f = cf & 31;
            raT[(pm << 10) + (f << 5) + c] = bfbits(ra[idx]);   // [pair][m][f][c]
            rmb[idx] = bfbits(rm[idx]);                          // [pair][m][c][f]
        }
    } else {
        const int idx = (blk - 1920)*256 + threadIdx.x;
        if (idx < HEADS*SS*BSTRIDE) {
            const int m = idx / (SS*BSTRIDE);
            const int rem = idx % (SS*BSTRIDE);
            const int s1 = rem / BSTRIDE, s2 = rem % BSTRIDE;
            float val = 0.f;
            if (s2 < SS) {
                const int i1 = s1/49, p1 = s1 - i1*49, h1 = p1/7, w1 = p1 - h1*7;
                const int j2 = s2/49, p2 = s2 - j2*49, h2 = p2/7, w2 = p2 - h2*7;
                const int rc = i1*169 + h1*13 + w1, cc = j2*169 + h2*13 + w2;
                val = bt[(rc - cc + 929)*8 + m];
            }
            biasM[idx] = val;
        }
    }
}

// ---------------- kernel 1: QKV projection via MFMA, split by tz ----------------
// grid = 3*768: bid3 = slab*3 + tz, so the 3 blocks reading one x-slab are adjacent
// (L2 co-hit; x 38.5 MB is L3-resident so re-reads stay off HBM). 1/3 the serial
// MFMA chain per block vs the fused version -> 3x wall parallelism.
__global__ __launch_bounds__(256) void k_qkv2(
    const float* __restrict__ x, const u16* __restrict__ wT,
    const float* __restrict__ bq, const float* __restrict__ bk, const float* __restrict__ bv,
    const int* __restrict__ atype,
    u16* __restrict__ q, u16* __restrict__ k, u16* __restrict__ v)
{
    __shared__ __align__(16) u16 As[64*ASTRIDE]; // 33792 B
    const int tid = threadIdx.x;
    const int w = tid >> 6, lane = tid & 63;
    const int g4 = lane >> 4, c16 = lane & 15;
    const int bid3 = blockIdx.x;
    const int tz = bid3 % 3;
    const int bid = bid3 / 3;                // (b*6+l)*64+n
    const int nwin = bid & 63;
    const int l = (bid >> 6) % LL;
    const int b = bid / (LL*NWIN);

    const float4* xp = (const float4*)(x + (size_t)bid * (PP*DIMM));
    for (int idx = tid; idx < 49*64; idx += 256) {
        const int row = idx >> 6, c4 = idx & 63;
        const float4 xv = xp[idx];
        ushort4 h;
        h.x = bfbits(xv.x); h.y = bfbits(xv.y); h.z = bfbits(xv.z); h.w = bfbits(xv.w);
        *(ushort4*)&As[row*ASTRIDE + c4*4] = h;
    }
    const ushort4 z4 = {0, 0, 0, 0};
    for (int idx = tid; idx < 15*66; idx += 256) {
        const int row = 49 + idx/66, c4 = idx%66;
        *(ushort4*)&As[row*ASTRIDE + c4*4] = z4;
    }
    __syncthreads();

    const int t = (l == 0) ? 0 : atype[0];
    const f32x4 zero4 = {0.f, 0.f, 0.f, 0.f};

    const u16* WT = wT + (size_t)(tz*2 + t)*65536;
    const float* bias = (tz == 0 ? bq : tz == 1 ? bk : bv) + t*DIMM;
    u16* dst = (tz == 0 ? q : tz == 1 ? k : v);
    const float scale = (tz == 0) ? 0.17677669529663687f : 1.0f;

    f32x4 acc[4][4];
    #pragma unroll
    for (int mm = 0; mm < 4; ++mm)
        #pragma unroll
        for (int nn = 0; nn < 4; ++nn) acc[mm][nn] = zero4;

    for (int ks = 0; ks < 8; ++ks) {
        bf16x8 a[4], bb[4];
        #pragma unroll
        for (int mm = 0; mm < 4; ++mm)
            a[mm] = *(const bf16x8*)&As[(mm*16 + c16)*ASTRIDE + ks*32 + g4*8];
        #pragma unroll
        for (int nn = 0; nn < 4; ++nn)
            bb[nn] = *(const bf16x8*)&WT[(size_t)(w*64 + nn*16 + c16)*256 + ks*32 + g4*8];
        #pragma unroll
        for (int mm = 0; mm < 4; ++mm)
            #pragma unroll
            for (int nn = 0; nn < 4; ++nn)
                acc[mm][nn] = mfma16(a[mm], bb[nn], acc[mm][nn]);
    }

    #pragma unroll
    for (int nn = 0; nn < 4; ++nn) {
        const int col = w*64 + nn*16 + c16;
        const float bval = bias[col];
        const int head = col >> 5, c = col & 31;
        const size_t base = (((size_t)(b*NWIN + nwin)*HEADS + head)*SS + l*PP)*CHN + c;
        #pragma unroll
        for (int mm = 0; mm < 4; ++mm) {
            #pragma unroll
            for (int r = 0; r < 4; ++r) {
                const int row = mm*16 + g4*4 + r;
                if (row < PP)
                    dst[base + (size_t)row*CHN] = bfbits((acc[mm][nn][r] + bval)*scale);
            }
        }
    }
}

// ---------------- kernel 2: MFMA hetero attention per (b,n,m) ----------------
// VERBATIM R5 structure (measured 134 us): acc[19] single softmax, vT+vT0, wbuf
// union (72/168), no min-waves bound. R6-R10 restructures all regressed; protect this.
__global__ __launch_bounds__(256) void k_attn(
    const u16* __restrict__ q, const u16* __restrict__ kk_, const u16* __restrict__ v,
    const u16* __restrict__ raT, const u16* __restrict__ rmb,
    const float* __restrict__ biasM, const int* __restrict__ atype,
    u16* __restrict__ o_pre)
{
    __shared__ __align__(16) u16 vT[32*VST];
    __shared__ __align__(16) u16 vT0[32*72];
    __shared__ __align__(16) u16 wbuf[4*16*PST];

    const int tid  = threadIdx.x;
    const int w    = tid >> 6;
    const int lane = tid & 63;
    const int g4   = lane >> 4;
    const int c16  = lane & 15;
    const int bid  = blockIdx.x;       // (b*64+n)*8+m
    const int m    = bid & 7;
    const int nwin = (bid >> 3) & 63;
    const int b    = bid >> 9;
    const int at   = atype[0];

    const size_t slab = (size_t)bid * (SS*CHN);
    const u16* qs  = q   + slab;
    const u16* ksg = kk_ + slab;
    const u16* vsg = v   + slab;
    const float* bm = biasM + (size_t)m*(SS*BSTRIDE);

    u16* wb = wbuf + w*(16*PST);

    // ---- zero pads + stage vT/vT0 (pads must be FINITE: 0*NaN=NaN, R6 lesson) ----
    for (int idx = tid; idx < 32*(VST - SS); idx += 256)
        vT[(idx/(VST - SS))*VST + SS + (idx%(VST - SS))] = 0;
    for (int idx = tid; idx < 32*15; idx += 256) vT0[(idx/15)*72 + 49 + (idx%15)] = 0;
    for (int idx = tid; idx < SS*CHN/2; idx += 256) {
        const int s2 = idx >> 4;
        const int f2 = (idx & 15) << 1;
        const unsigned int val = *(const unsigned int*)(vsg + s2*CHN + f2);
        const u16 v0 = (u16)(val & 0xffff), v1 = (u16)(val >> 16);
        vT[f2*VST + s2]     = v0;
        vT[(f2+1)*VST + s2] = v1;
        if (s2 < 49) { vT0[f2*72 + s2] = v0; vT0[(f2+1)*72 + s2] = v1; }
    }
    __syncthreads();

    const f32x4 zero4 = {0.f, 0.f, 0.f, 0.f};

    for (int job = w; job < 20; job += 4) {
        const int tile = (job == 19) ? 3 : job;
        const int tiv  = (job <= 3) ? 0 : at;
        const int pair0 = tiv*2;
        const int pair1 = tiv*2 + at;

        // ---- phase A: qw build (wb as [16][72]) ----
        const int rowA = tile*16 + c16;
        const bf16x8 aq = *(const bf16x8*)(qs + rowA*CHN + g4*8);
        {
            const u16* base0 = raT + (pair0*HEADS + m)*1024;
            const u16* base1 = raT + (pair1*HEADS + m)*1024;
            const bf16x8 b00 = *(const bf16x8*)(base0 + (c16     )*32 + g4*8);
            const bf16x8 b01 = *(const bf16x8*)(base0 + (16 + c16)*32 + g4*8);
            const bf16x8 b10 = *(const bf16x8*)(base1 + (c16     )*32 + g4*8);
            const bf16x8 b11 = *(const bf16x8*)(base1 + (16 + c16)*32 + g4*8);
            const f32x4 cqw00 = mfma16(aq, b00, zero4);
            const f32x4 cqw01 = mfma16(aq, b01, zero4);
            const f32x4 cqw10 = mfma16(aq, b10, zero4);
            const f32x4 cqw11 = mfma16(aq, b11, zero4);
            #pragma unroll
            for (int r = 0; r < 4; ++r) {
                const int row = g4*4 + r;
                wb[row*72 +      c16] = bfbits(cqw00[r]);
                wb[row*72 + 16 + c16] = bfbits(cqw01[r]);
                wb[row*72 + 32 + c16] = bfbits(cqw10[r]);
                wb[row*72 + 48 + c16] = bfbits(cqw11[r]);
            }
        }
        const bf16x8 A0 = *(const bf16x8*)(wb + c16*72 +      g4*8);
        const bf16x8 A1 = *(const bf16x8*)(wb + c16*72 + 32 + g4*8);

        // ---- phase B: sim = qw_sel @ k^T ----
        f32x4 acc[19];
        #pragma unroll
        for (int t = 0; t < 3; ++t) {
            const bf16x8 bk = *(const bf16x8*)(ksg + (t*16 + c16)*CHN + g4*8);
            acc[t] = mfma16(A0, bk, zero4);
        }
        {
            const bf16x8 bk = *(const bf16x8*)(ksg + (3*16 + c16)*CHN + g4*8);
            const f32x4 cA = mfma16(A0, bk, zero4);
            const f32x4 cB = mfma16(A1, bk, zero4);
            #pragma unroll
            for (int r = 0; r < 4; ++r) acc[3][r] = (c16 == 0) ? cA[r] : cB[r];
        }
        #pragma unroll
        for (int t = 4; t < 19; ++t) {
            const bf16x8 bk = *(const bf16x8*)(ksg + (t*16 + c16)*CHN + g4*8);
            acc[t] = mfma16(A1, bk, zero4);
        }

        // ---- bias add: coalesced rows from precomputed biasM ----
        const float* bmrow[4];
        #pragma unroll
        for (int r = 0; r < 4; ++r) {
            const int s1r = tile*16 + g4*4 + r;
            const int s1c = (s1r < SS) ? s1r : 293;
            bmrow[r] = bm + (size_t)s1c*BSTRIDE;
        }
        #pragma unroll
        for (int t = 0; t < 19; ++t)
            #pragma unroll
            for (int r = 0; r < 4; ++r)
                acc[t][r] += bmrow[r][t*16 + c16];
        #pragma unroll
        for (int r = 0; r < 4; ++r)
            acc[18][r] = (c16 < 6) ? acc[18][r] : -1e30f;

        // ---- softmax over s2 ----
        float mx[4], sm[4];
        #pragma unroll
        for (int r = 0; r < 4; ++r) mx[r] = -1e30f;
        #pragma unroll
        for (int t = 0; t < 19; ++t)
            #pragma unroll
            for (int r = 0; r < 4; ++r) mx[r] = fmaxf(mx[r], acc[t][r]);
        #pragma unroll
        for (int off = 1; off < 16; off <<= 1)
            #pragma unroll
            for (int r = 0; r < 4; ++r) mx[r] = fmaxf(mx[r], __shfl_xor(mx[r], off));
        #pragma unroll
        for (int r = 0; r < 4; ++r) sm[r] = 0.f;
        #pragma unroll
        for (int t = 0; t < 19; ++t)
            #pragma unroll
            for (int r = 0; r < 4; ++r) { const float e = __expf(acc[t][r] - mx[r]); acc[t][r] = e; sm[r] += e; }
        #pragma unroll
        for (int off = 1; off < 16; off <<= 1)
            #pragma unroll
            for (int r = 0; r < 4; ++r) sm[r] += __shfl_xor(sm[r], off);
        #pragma unroll
        for (int r = 0; r < 4; ++r) {
            const float inv = 1.0f / sm[r];
            #pragma unroll
            for (int t = 0; t < 19; ++t) acc[t][r] *= inv;
        }

        // ---- phase D pass 1: tiles 0..9 (ks 0..4), wb as [16][PST] ----
        f32x4 aggF0a = zero4, aggF0b = zero4, aggF1a = zero4, aggF1b = zero4;
        f32x4 agg00 = zero4, agg01 = zero4;
        bf16x8 asave0, asave1;
        #pragma unroll
        for (int t = 0; t < 10; ++t)
            #pragma unroll
            for (int r = 0; r < 4; ++r)
                wb[(g4*4 + r)*PST + t*16 + c16] = bfbits(acc[t][r]);
        #pragma unroll
        for (int ks = 0; ks < 5; ++ks) {
            const bf16x8 ap  = *(const bf16x8*)(wb + c16*PST + ks*32 + g4*8);
            const bf16x8 bv0 = *(const bf16x8*)(vT + (c16     )*VST + ks*32 + g4*8);
            const bf16x8 bv1 = *(const bf16x8*)(vT + (16 + c16)*VST + ks*32 + g4*8);
            if (ks & 1) { aggF0b = mfma16(ap, bv0, aggF0b); aggF1b = mfma16(ap, bv1, aggF1b); }
            else        { aggF0a = mfma16(ap, bv0, aggF0a); aggF1a = mfma16(ap, bv1, aggF1a); }
            if (ks == 0) asave0 = ap;
            if (ks == 1) asave1 = ap;
        }

        // ---- phase D pass 2: tiles 10..18 + zero pad (ks 5..9) ----
        #pragma unroll
        for (int t2 = 0; t2 < 9; ++t2)
            #pragma unroll
            for (int r = 0; r < 4; ++r)
                wb[(g4*4 + r)*PST + t2*16 + c16] = bfbits(acc[10 + t2][r]);
        #pragma unroll
        for (int r = 0; r < 4; ++r)
            wb[(g4*4 + r)*PST + 9*16 + c16] = 0;
        #pragma unroll
        for (int ks2 = 0; ks2 < 5; ++ks2) {
            const int ks = 5 + ks2;
            const bf16x8 ap  = *(const bf16x8*)(wb + c16*PST + ks2*32 + g4*8);
            const bf16x8 bv0 = *(const bf16x8*)(vT + (c16     )*VST + ks*32 + g4*8);
            const bf16x8 bv1 = *(const bf16x8*)(vT + (16 + c16)*VST + ks*32 + g4*8);
            if (ks2 & 1) { aggF0b = mfma16(ap, bv0, aggF0b); aggF1b = mfma16(ap, bv1, aggF1b); }
            else         { aggF0a = mfma16(ap, bv0, aggF0a); aggF1a = mfma16(ap, bv1, aggF1a); }
        }

        // ---- j=0 part via zero-padded vT0 ----
        {
            const bf16x8 b00 = *(const bf16x8*)(vT0 + (c16     )*72 +      g4*8);
            const bf16x8 b01 = *(const bf16x8*)(vT0 + (16 + c16)*72 +      g4*8);
            const bf16x8 b10 = *(const bf16x8*)(vT0 + (c16     )*72 + 32 + g4*8);
            const bf16x8 b11 = *(const bf16x8*)(vT0 + (16 + c16)*72 + 32 + g4*8);
            agg00 = mfma16(asave0, b00, agg00); agg00 = mfma16(asave1, b10, agg00);
            agg01 = mfma16(asave0, b01, agg01); agg01 = mfma16(asave1, b11, agg01);
        }
        const f32x4 aggF0 = aggF0a + aggF0b;
        const f32x4 aggF1 = aggF1a + aggF1b;
        const f32x4 agg10 = aggF0 - agg00;
        const f32x4 agg11 = aggF1 - agg01;

        // ---- phase E: msg transform (wb as [16][72] again) ----
        #pragma unroll
        for (int r = 0; r < 4; ++r) {
            const int row = g4*4 + r;
            wb[row*72 +      c16] = bfbits(agg00[r]);
            wb[row*72 + 16 + c16] = bfbits(agg01[r]);
            wb[row*72 + 32 + c16] = bfbits(agg10[r]);
            wb[row*72 + 48 + c16] = bfbits(agg11[r]);
        }
        const bf16x8 aA0 = *(const bf16x8*)(wb + c16*72 +      g4*8);
        const bf16x8 aA1 = *(const bf16x8*)(wb + c16*72 + 32 + g4*8);
        const u16* mb0 = rmb + (pair0*HEADS + m)*1024;
        const u16* mb1 = rmb + (pair1*HEADS + m)*1024;
        const bf16x8 bm00 = *(const bf16x8*)(mb0 + (c16     )*32 + g4*8);
        const bf16x8 bm01 = *(const bf16x8*)(mb0 + (16 + c16)*32 + g4*8);
        const bf16x8 bm10 = *(const bf16x8*)(mb1 + (c16     )*32 + g4*8);
        const bf16x8 bm11 = *(const bf16x8*)(mb1 + (16 + c16)*32 + g4*8);
        f32x4 out0 = mfma16(aA0, bm00, zero4); out0 = mfma16(aA1, bm10, out0);
        f32x4 out1 = mfma16(aA0, bm01, zero4); out1 = mfma16(aA1, bm11, out1);

        // ---- store bf16 ----
        #pragma unroll
        for (int r = 0; r < 4; ++r) {
            const int s1row = tile*16 + g4*4 + r;
            bool valid = (s1row < SS);
            if (job == 3)  valid = valid && (s1row == 48);
            if (job == 19) valid = valid && (s1row >= 49);
            if (valid) {
                const int i = s1row / 49, p = s1row - i*49;
                const size_t rb = ((size_t)((b*LL + i)*NWIN + nwin)*PP + p)*DIMM + m*CHN;
                o_pre[rb + c16]      = bfbits(out0[r]);
                o_pre[rb + 16 + c16] = bfbits(out1[r]);
            }
        }
    }
}

// ---------------- kernel 3: out = o_pre @ Wo^T via MFMA, de-staged ----------------
// o_preb is already bf16: A-fragments load directly from global (25 KB slab,
// L1-resident across the 8 ks re-reads). No LDS, no staging pass, no barrier.
// Rows 49..63 clamp to row 48 (finite; results discarded at store).
__global__ __launch_bounds__(256) void k_out2(
    const u16* __restrict__ pre, const u16* __restrict__ Wob,
    float* __restrict__ out)
{
    const int tid = threadIdx.x;
    const int w = tid >> 6, lane = tid & 63;
    const int g4 = lane >> 4, c16 = lane & 15;
    const int bid = blockIdx.x;
    const u16* ps = pre + (size_t)bid * (PP*DIMM);

    int rowc[4];
    #pragma unroll
    for (int mm = 0; mm < 4; ++mm) {
        const int r0 = mm*16 + c16;
        rowc[mm] = (r0 < PP) ? r0 : (PP - 1);
    }

    const f32x4 zero4 = {0.f, 0.f, 0.f, 0.f};
    f32x4 acc[4][4];
    #pragma unroll
    for (int mm = 0; mm < 4; ++mm)
        #pragma unroll
        for (int nn = 0; nn < 4; ++nn) acc[mm][nn] = zero4;

    for (int ks = 0; ks < 8; ++ks) {
        bf16x8 a[4], bb[4];
        #pragma unroll
        for (int mm = 0; mm < 4; ++mm)
            a[mm] = *(const bf16x8*)(ps + (size_t)rowc[mm]*DIMM + ks*32 + g4*8);
        #pragma unroll
        for (int nn = 0; nn < 4; ++nn)
            bb[nn] = *(const bf16x8*)&Wob[(size_t)(w*64 + nn*16 + c16)*256 + ks*32 + g4*8];
        #pragma unroll
        for (int mm = 0; mm < 4; ++mm)
            #pragma unroll
            for (int nn = 0; nn < 4; ++nn)
                acc[mm][nn] = mfma16(a[mm], bb[nn], acc[mm][nn]);
    }

    float* op = out + (size_t)bid * (PP*DIMM);
    #pragma unroll
    for (int nn = 0; nn < 4; ++nn) {
        const int col = w*64 + nn*16 + c16;
        #pragma unroll
        for (int mm = 0; mm < 4; ++mm) {
            #pragma unroll
            for (int r = 0; r < 4; ++r) {
                const int row = mm*16 + g4*4 + r;
                if (row < PP) op[(size_t)row*DIMM + col] = acc[mm][nn][r];
            }
        }
    }
}

extern "C" void kernel_launch(void* const* d_in, const int* in_sizes, int n_in,
                              void* d_out, int out_size, void* d_ws, size_t ws_size,
                              hipStream_t stream)
{
    (void)in_sizes; (void)n_in; (void)out_size; (void)ws_size;
    const float* x        = (const float*)d_in[0];
    const float* Wq       = (const float*)d_in[1];
    const float* bq       = (const float*)d_in[2];
    const float* Wk       = (const float*)d_in[3];
    const float* bk       = (const float*)d_in[4];
    const float* Wv       = (const float*)d_in[5];
    const float* bv       = (const float*)d_in[6];
    const float* rel_att  = (const float*)d_in[7];
    const float* rel_msg  = (const float*)d_in[8];
    const float* bias_tab = (const float*)d_in[9];
    const float* Wo       = (const float*)d_in[10];
    const int*   atype    = (const int*)d_in[11];
    float* out = (float*)d_out;

    // workspace layout (bytes):
    //  wT    bf16: [0, 786432)
    //  Wob   bf16: [786432, 917504)
    //  raT   bf16: [917504, 983040)
    //  rmb   bf16: [983040, 1048576)
    //  biasM f32 : [1048576, 3908608)
    //  qb, kb, vb, o_preb bf16: 4 x 19267584  -> total 80,978,944 B
    char* ws = (char*)d_ws;
    u16* wT     = (u16*)ws;
    u16* Wob    = (u16*)(ws + 786432);
    u16* raT    = (u16*)(ws + 917504);
    u16* rmb    = (u16*)(ws + 983040);
    float* biasM= (float*)(ws + 1048576);
    u16* qb     = (u16*)(ws + 3908608);
    u16* kb     = (u16*)(ws + 3908608 + 1ull*19267584);
    u16* vb     = (u16*)(ws + 3908608 + 2ull*19267584);
    u16* o_preb = (u16*)(ws + 3908608 + 3ull*19267584);

    k_prep<<<4713, 256, 0, stream>>>(Wq, Wk, Wv, Wo, rel_att, rel_msg, bias_tab,
                                     wT, Wob, raT, rmb, biasM);
    k_qkv2<<<3*BB*LL*NWIN, 256, 0, stream>>>(x, wT, bq, bk, bv, atype, qb, kb, vb);
    k_attn<<<BB*NWIN*HEADS, 256, 0, stream>>>(qb, kb, vb, raT, rmb, biasM, atype, o_preb);
    k_out2<<<BB*LL*NWIN, 256, 0, stream>>>(o_preb, Wob, out);
}

// Round 12
// 222.621 us; speedup vs baseline: 1.7537x; 1.0059x over previous
//
#include <hip/hip_runtime.h>
#include <hip/hip_bf16.h>

typedef __hip_bfloat16 bf16;
typedef unsigned short u16;
typedef short bf16x8 __attribute__((ext_vector_type(8)));
typedef float f32x4  __attribute__((ext_vector_type(4)));

// problem constants (fixed instance)
#define BB    2
#define LL    6
#define NWIN  64     // X*Y
#define PP    49     // w1*w2
#define DIMM  256
#define HEADS 8
#define CHN   32
#define SS    294    // LL*PP
#define BSTRIDE 304  // biasM row stride (f32)
// k_attn strides: R5-proven pair (134 us). R9 (164/308) was slower despite fewer
// bank conflicts - counters are not time; keep 328/168. k_attn is FROZEN (R6-R10
// restructures all regressed).
#define VST 328
#define PST 168

__device__ __forceinline__ u16 bfbits(float x) { return __bfloat16_as_ushort(__float2bfloat16(x)); }
__device__ __forceinline__ unsigned int pk2(float a, float b) {
    return (unsigned int)bfbits(a) | ((unsigned int)bfbits(b) << 16);
}
__device__ __forceinline__ f32x4 mfma16(bf16x8 a, bf16x8 b, f32x4 c) {
    return __builtin_amdgcn_mfma_f32_16x16x32_bf16(a, b, c, 0, 0, 0);
}

// ---------------- merged prep kernel ----------------
// blocks [0,384):     W transpose f32->bf16, LDS-tiled (coalesced both sides)
// blocks [384,640):   Wo -> bf16 elementwise
// blocks [640,768):   rel weights -> bf16 (att transposed)
// blocks [768,3561):  biasM build
// blocks [3561,9705): x -> bf16, PRE-SWIZZLED slab layout for k_qkv2:
//                     xb[slab][row][col] = x[slab][row][col ^ ((row&7)<<3)],
//                     rows 49..63 zeroed (finite! R6 NaN lesson).
__global__ __launch_bounds__(256) void k_prep(
    const float* __restrict__ Wq, const float* __restrict__ Wk, const float* __restrict__ Wv,
    const float* __restrict__ Wo, const float* __restrict__ ra, const float* __restrict__ rm,
    const float* __restrict__ bt, const float* __restrict__ x,
    u16* __restrict__ wT, u16* __restrict__ Wob, u16* __restrict__ raT, u16* __restrict__ rmb,
    float* __restrict__ biasM, u16* __restrict__ xb)
{
    const int blk = blockIdx.x;
    const int tid = threadIdx.x;
    if (blk < 384) {
        __shared__ float tle[32][33];
        const int mat = blk >> 6, tile = blk & 63;
        const int bx = tile & 7, by = tile >> 3;
        const int tx = tid & 31, ty = tid >> 5;   // 32x8
        const int tz = mat >> 1, t = mat & 1;
        const float* W = (tz == 0 ? Wq : tz == 1 ? Wk : Wv) + t*65536;
        #pragma unroll
        for (int r = 0; r < 32; r += 8)
            tle[ty + r][tx] = W[(by*32 + ty + r)*256 + bx*32 + tx];
        __syncthreads();
        #pragma unroll
        for (int r = 0; r < 32; r += 8)
            wT[mat*65536 + (bx*32 + ty + r)*256 + by*32 + tx] = bfbits(tle[tx][ty + r]);
    } else if (blk < 640) {
        const int idx = (blk - 384)*256 + tid;
        Wob[idx] = bfbits(Wo[idx]);
    } else if (blk < 768) {
        const int idx = (blk - 640)*256 + tid;
        const int pm = idx >> 10, cf = idx & 1023, c = cf >> 5, f = cf & 31;
        raT[(pm << 10) + (f << 5) + c] = bfbits(ra[idx]);   // [pair][m][f][c]
        rmb[idx] = bfbits(rm[idx]);                          // [pair][m][c][f]
    } else if (blk < 3561) {
        const int idx = (blk - 768)*256 + tid;
        if (idx < HEADS*SS*BSTRIDE) {
            const int m = idx / (SS*BSTRIDE);
            const int rem = idx % (SS*BSTRIDE);
            const int s1 = rem / BSTRIDE, s2 = rem % BSTRIDE;
            float val = 0.f;
            if (s2 < SS) {
                const int i1 = s1/49, p1 = s1 - i1*49, h1 = p1/7, w1 = p1 - h1*7;
                const int j2 = s2/49, p2 = s2 - j2*49, h2 = p2/7, w2 = p2 - h2*7;
                const int rc = i1*169 + h1*13 + w1, cc = j2*169 + h2*13 + w2;
                val = bt[(rc - cc + 929)*8 + m];
            }
            biasM[idx] = val;
        }
    } else {
        // x -> swizzled bf16 slabs: idx = ((slab*64)+row)*32 + grp, 8 u16 per thread
        const int idx = (blk - 3561)*256 + tid;   // < 768*64*32 = 1,572,864 exactly
        const int grp  = idx & 31;
        const int row  = (idx >> 5) & 63;
        const int slab = idx >> 11;
        uint4 o = make_uint4(0u, 0u, 0u, 0u);
        if (row < PP) {
            const float* s = x + (size_t)slab*(PP*DIMM) + row*DIMM + ((grp ^ (row & 7)) << 3);
            const float4 a = *(const float4*)s;
            const float4 c = *(const float4*)(s + 4);
            o.x = pk2(a.x, a.y); o.y = pk2(a.z, a.w);
            o.z = pk2(c.x, c.y); o.w = pk2(c.z, c.w);
        }
        *(uint4*)(xb + (size_t)slab*16384 + row*256 + grp*8) = o;
    }
}

// ---------------- kernel 1: QKV projection via MFMA, split by tz ----------------
// Stages the pre-swizzled bf16 slab with a raw 32 KB vector copy (no cvt, no
// zero-fill). A-fragment reads apply the same XOR involution (rule: swizzle
// both-sides-or-neither) -> rows 0..7 spread across all banks, rows 8..15
// duplicate = 2-way = free.
__global__ __launch_bounds__(256) void k_qkv2(
    const u16* __restrict__ xb, const u16* __restrict__ wT,
    const float* __restrict__ bq, const float* __restrict__ bk, const float* __restrict__ bv,
    const int* __restrict__ atype,
    u16* __restrict__ q, u16* __restrict__ k, u16* __restrict__ v)
{
    __shared__ __align__(16) u16 As[64*256]; // 32768 B, linear (swizzled content)
    const int tid = threadIdx.x;
    const int w = tid >> 6, lane = tid & 63;
    const int g4 = lane >> 4, c16 = lane & 15;
    const int bid3 = blockIdx.x;
    const int tz = bid3 % 3;
    const int bid = bid3 / 3;                // (b*6+l)*64+n
    const int nwin = bid & 63;
    const int l = (bid >> 6) % LL;
    const int b = bid / (LL*NWIN);

    const uint4* src = (const uint4*)(xb + (size_t)bid*16384);
    for (int j = tid; j < 2048; j += 256)
        ((uint4*)As)[j] = src[j];
    __syncthreads();

    const int t = (l == 0) ? 0 : atype[0];
    const f32x4 zero4 = {0.f, 0.f, 0.f, 0.f};

    const u16* WT = wT + (size_t)(tz*2 + t)*65536;
    const float* bias = (tz == 0 ? bq : tz == 1 ? bk : bv) + t*DIMM;
    u16* dst = (tz == 0 ? q : tz == 1 ? k : v);
    const float scale = (tz == 0) ? 0.17677669529663687f : 1.0f;

    f32x4 acc[4][4];
    #pragma unroll
    for (int mm = 0; mm < 4; ++mm)
        #pragma unroll
        for (int nn = 0; nn < 4; ++nn) acc[mm][nn] = zero4;

    for (int ks = 0; ks < 8; ++ks) {
        bf16x8 a[4], bb[4];
        #pragma unroll
        for (int mm = 0; mm < 4; ++mm) {
            const int row = mm*16 + c16;
            a[mm] = *(const bf16x8*)&As[row*256 + ((ks*32 + g4*8) ^ ((row & 7) << 3))];
        }
        #pragma unroll
        for (int nn = 0; nn < 4; ++nn)
            bb[nn] = *(const bf16x8*)&WT[(size_t)(w*64 + nn*16 + c16)*256 + ks*32 + g4*8];
        #pragma unroll
        for (int mm = 0; mm < 4; ++mm)
            #pragma unroll
            for (int nn = 0; nn < 4; ++nn)
                acc[mm][nn] = mfma16(a[mm], bb[nn], acc[mm][nn]);
    }

    #pragma unroll
    for (int nn = 0; nn < 4; ++nn) {
        const int col = w*64 + nn*16 + c16;
        const float bval = bias[col];
        const int head = col >> 5, c = col & 31;
        const size_t base = (((size_t)(b*NWIN + nwin)*HEADS + head)*SS + l*PP)*CHN + c;
        #pragma unroll
        for (int mm = 0; mm < 4; ++mm) {
            #pragma unroll
            for (int r = 0; r < 4; ++r) {
                const int row = mm*16 + g4*4 + r;
                if (row < PP)
                    dst[base + (size_t)row*CHN] = bfbits((acc[mm][nn][r] + bval)*scale);
            }
        }
    }
}

// ---------------- kernel 2: MFMA hetero attention per (b,n,m) ----------------
// VERBATIM R5/R11 structure (measured 134.6 us). FROZEN: R6-R10 restructures
// (online-split, stride swap, two-pass recompute, forced launch_bounds) all lost.
__global__ __launch_bounds__(256) void k_attn(
    const u16* __restrict__ q, const u16* __restrict__ kk_, const u16* __restrict__ v,
    const u16* __restrict__ raT, const u16* __restrict__ rmb,
    const float* __restrict__ biasM, const int* __restrict__ atype,
    u16* __restrict__ o_pre)
{
    __shared__ __align__(16) u16 vT[32*VST];
    __shared__ __align__(16) u16 vT0[32*72];
    __shared__ __align__(16) u16 wbuf[4*16*PST];

    const int tid  = threadIdx.x;
    const int w    = tid >> 6;
    const int lane = tid & 63;
    const int g4   = lane >> 4;
    const int c16  = lane & 15;
    const int bid  = blockIdx.x;       // (b*64+n)*8+m
    const int m    = bid & 7;
    const int nwin = (bid >> 3) & 63;
    const int b    = bid >> 9;
    const int at   = atype[0];

    const size_t slab = (size_t)bid * (SS*CHN);
    const u16* qs  = q   + slab;
    const u16* ksg = kk_ + slab;
    const u16* vsg = v   + slab;
    const float* bm = biasM + (size_t)m*(SS*BSTRIDE);

    u16* wb = wbuf + w*(16*PST);

    // ---- zero pads + stage vT/vT0 (pads must be FINITE: 0*NaN=NaN, R6 lesson) ----
    for (int idx = tid; idx < 32*(VST - SS); idx += 256)
        vT[(idx/(VST - SS))*VST + SS + (idx%(VST - SS))] = 0;
    for (int idx = tid; idx < 32*15; idx += 256) vT0[(idx/15)*72 + 49 + (idx%15)] = 0;
    for (int idx = tid; idx < SS*CHN/2; idx += 256) {
        const int s2 = idx >> 4;
        const int f2 = (idx & 15) << 1;
        const unsigned int val = *(const unsigned int*)(vsg + s2*CHN + f2);
        const u16 v0 = (u16)(val & 0xffff), v1 = (u16)(val >> 16);
        vT[f2*VST + s2]     = v0;
        vT[(f2+1)*VST + s2] = v1;
        if (s2 < 49) { vT0[f2*72 + s2] = v0; vT0[(f2+1)*72 + s2] = v1; }
    }
    __syncthreads();

    const f32x4 zero4 = {0.f, 0.f, 0.f, 0.f};

    for (int job = w; job < 20; job += 4) {
        const int tile = (job == 19) ? 3 : job;
        const int tiv  = (job <= 3) ? 0 : at;
        const int pair0 = tiv*2;
        const int pair1 = tiv*2 + at;

        // ---- phase A: qw build (wb as [16][72]) ----
        const int rowA = tile*16 + c16;
        const bf16x8 aq = *(const bf16x8*)(qs + rowA*CHN + g4*8);
        {
            const u16* base0 = raT + (pair0*HEADS + m)*1024;
            const u16* base1 = raT + (pair1*HEADS + m)*1024;
            const bf16x8 b00 = *(const bf16x8*)(base0 + (c16     )*32 + g4*8);
            const bf16x8 b01 = *(const bf16x8*)(base0 + (16 + c16)*32 + g4*8);
            const bf16x8 b10 = *(const bf16x8*)(base1 + (c16     )*32 + g4*8);
            const bf16x8 b11 = *(const bf16x8*)(base1 + (16 + c16)*32 + g4*8);
            const f32x4 cqw00 = mfma16(aq, b00, zero4);
            const f32x4 cqw01 = mfma16(aq, b01, zero4);
            const f32x4 cqw10 = mfma16(aq, b10, zero4);
            const f32x4 cqw11 = mfma16(aq, b11, zero4);
            #pragma unroll
            for (int r = 0; r < 4; ++r) {
                const int row = g4*4 + r;
                wb[row*72 +      c16] = bfbits(cqw00[r]);
                wb[row*72 + 16 + c16] = bfbits(cqw01[r]);
                wb[row*72 + 32 + c16] = bfbits(cqw10[r]);
                wb[row*72 + 48 + c16] = bfbits(cqw11[r]);
            }
        }
        const bf16x8 A0 = *(const bf16x8*)(wb + c16*72 +      g4*8);
        const bf16x8 A1 = *(const bf16x8*)(wb + c16*72 + 32 + g4*8);

        // ---- phase B: sim = qw_sel @ k^T ----
        f32x4 acc[19];
        #pragma unroll
        for (int t = 0; t < 3; ++t) {
            const bf16x8 bk = *(const bf16x8*)(ksg + (t*16 + c16)*CHN + g4*8);
            acc[t] = mfma16(A0, bk, zero4);
        }
        {
            const bf16x8 bk = *(const bf16x8*)(ksg + (3*16 + c16)*CHN + g4*8);
            const f32x4 cA = mfma16(A0, bk, zero4);
            const f32x4 cB = mfma16(A1, bk, zero4);
            #pragma unroll
            for (int r = 0; r < 4; ++r) acc[3][r] = (c16 == 0) ? cA[r] : cB[r];
        }
        #pragma unroll
        for (int t = 4; t < 19; ++t) {
            const bf16x8 bk = *(const bf16x8*)(ksg + (t*16 + c16)*CHN + g4*8);
            acc[t] = mfma16(A1, bk, zero4);
        }

        // ---- bias add: coalesced rows from precomputed biasM ----
        const float* bmrow[4];
        #pragma unroll
        for (int r = 0; r < 4; ++r) {
            const int s1r = tile*16 + g4*4 + r;
            const int s1c = (s1r < SS) ? s1r : 293;
            bmrow[r] = bm + (size_t)s1c*BSTRIDE;
        }
        #pragma unroll
        for (int t = 0; t < 19; ++t)
            #pragma unroll
            for (int r = 0; r < 4; ++r)
                acc[t][r] += bmrow[r][t*16 + c16];
        #pragma unroll
        for (int r = 0; r < 4; ++r)
            acc[18][r] = (c16 < 6) ? acc[18][r] : -1e30f;

        // ---- softmax over s2 ----
        float mx[4], sm[4];
        #pragma unroll
        for (int r = 0; r < 4; ++r) mx[r] = -1e30f;
        #pragma unroll
        for (int t = 0; t < 19; ++t)
            #pragma unroll
            for (int r = 0; r < 4; ++r) mx[r] = fmaxf(mx[r], acc[t][r]);
        #pragma unroll
        for (int off = 1; off < 16; off <<= 1)
            #pragma unroll
            for (int r = 0; r < 4; ++r) mx[r] = fmaxf(mx[r], __shfl_xor(mx[r], off));
        #pragma unroll
        for (int r = 0; r < 4; ++r) sm[r] = 0.f;
        #pragma unroll
        for (int t = 0; t < 19; ++t)
            #pragma unroll
            for (int r = 0; r < 4; ++r) { const float e = __expf(acc[t][r] - mx[r]); acc[t][r] = e; sm[r] += e; }
        #pragma unroll
        for (int off = 1; off < 16; off <<= 1)
            #pragma unroll
            for (int r = 0; r < 4; ++r) sm[r] += __shfl_xor(sm[r], off);
        #pragma unroll
        for (int r = 0; r < 4; ++r) {
            const float inv = 1.0f / sm[r];
            #pragma unroll
            for (int t = 0; t < 19; ++t) acc[t][r] *= inv;
        }

        // ---- phase D pass 1: tiles 0..9 (ks 0..4), wb as [16][PST] ----
        f32x4 aggF0a = zero4, aggF0b = zero4, aggF1a = zero4, aggF1b = zero4;
        f32x4 agg00 = zero4, agg01 = zero4;
        bf16x8 asave0, asave1;
        #pragma unroll
        for (int t = 0; t < 10; ++t)
            #pragma unroll
            for (int r = 0; r < 4; ++r)
                wb[(g4*4 + r)*PST + t*16 + c16] = bfbits(acc[t][r]);
        #pragma unroll
        for (int ks = 0; ks < 5; ++ks) {
            const bf16x8 ap  = *(const bf16x8*)(wb + c16*PST + ks*32 + g4*8);
            const bf16x8 bv0 = *(const bf16x8*)(vT + (c16     )*VST + ks*32 + g4*8);
            const bf16x8 bv1 = *(const bf16x8*)(vT + (16 + c16)*VST + ks*32 + g4*8);
            if (ks & 1) { aggF0b = mfma16(ap, bv0, aggF0b); aggF1b = mfma16(ap, bv1, aggF1b); }
            else        { aggF0a = mfma16(ap, bv0, aggF0a); aggF1a = mfma16(ap, bv1, aggF1a); }
            if (ks == 0) asave0 = ap;
            if (ks == 1) asave1 = ap;
        }

        // ---- phase D pass 2: tiles 10..18 + zero pad (ks 5..9) ----
        #pragma unroll
        for (int t2 = 0; t2 < 9; ++t2)
            #pragma unroll
            for (int r = 0; r < 4; ++r)
                wb[(g4*4 + r)*PST + t2*16 + c16] = bfbits(acc[10 + t2][r]);
        #pragma unroll
        for (int r = 0; r < 4; ++r)
            wb[(g4*4 + r)*PST + 9*16 + c16] = 0;
        #pragma unroll
        for (int ks2 = 0; ks2 < 5; ++ks2) {
            const int ks = 5 + ks2;
            const bf16x8 ap  = *(const bf16x8*)(wb + c16*PST + ks2*32 + g4*8);
            const bf16x8 bv0 = *(const bf16x8*)(vT + (c16     )*VST + ks*32 + g4*8);
            const bf16x8 bv1 = *(const bf16x8*)(vT + (16 + c16)*VST + ks*32 + g4*8);
            if (ks2 & 1) { aggF0b = mfma16(ap, bv0, aggF0b); aggF1b = mfma16(ap, bv1, aggF1b); }
            else         { aggF0a = mfma16(ap, bv0, aggF0a); aggF1a = mfma16(ap, bv1, aggF1a); }
        }

        // ---- j=0 part via zero-padded vT0 ----
        {
            const bf16x8 b00 = *(const bf16x8*)(vT0 + (c16     )*72 +      g4*8);
            const bf16x8 b01 = *(const bf16x8*)(vT0 + (16 + c16)*72 +      g4*8);
            const bf16x8 b10 = *(const bf16x8*)(vT0 + (c16     )*72 + 32 + g4*8);
            const bf16x8 b11 = *(const bf16x8*)(vT0 + (16 + c16)*72 + 32 + g4*8);
            agg00 = mfma16(asave0, b00, agg00); agg00 = mfma16(asave1, b10, agg00);
            agg01 = mfma16(asave0, b01, agg01); agg01 = mfma16(asave1, b11, agg01);
        }
        const f32x4 aggF0 = aggF0a + aggF0b;
        const f32x4 aggF1 = aggF1a + aggF1b;
        const f32x4 agg10 = aggF0 - agg00;
        const f32x4 agg11 = aggF1 - agg01;

        // ---- phase E: msg transform (wb as [16][72] again) ----
        #pragma unroll
        for (int r = 0; r < 4; ++r) {
            const int row = g4*4 + r;
            wb[row*72 +      c16] = bfbits(agg00[r]);
            wb[row*72 + 16 + c16] = bfbits(agg01[r]);
            wb[row*72 + 32 + c16] = bfbits(agg10[r]);
            wb[row*72 + 48 + c16] = bfbits(agg11[r]);
        }
        const bf16x8 aA0 = *(const bf16x8*)(wb + c16*72 +      g4*8);
        const bf16x8 aA1 = *(const bf16x8*)(wb + c16*72 + 32 + g4*8);
        const u16* mb0 = rmb + (pair0*HEADS + m)*1024;
        const u16* mb1 = rmb + (pair1*HEADS + m)*1024;
        const bf16x8 bm00 = *(const bf16x8*)(mb0 + (c16     )*32 + g4*8);
        const bf16x8 bm01 = *(const bf16x8*)(mb0 + (16 + c16)*32 + g4*8);
        const bf16x8 bm10 = *(const bf16x8*)(mb1 + (c16     )*32 + g4*8);
        const bf16x8 bm11 = *(const bf16x8*)(mb1 + (16 + c16)*32 + g4*8);
        f32x4 out0 = mfma16(aA0, bm00, zero4); out0 = mfma16(aA1, bm10, out0);
        f32x4 out1 = mfma16(aA0, bm01, zero4); out1 = mfma16(aA1, bm11, out1);

        // ---- store bf16 ----
        #pragma unroll
        for (int r = 0; r < 4; ++r) {
            const int s1row = tile*16 + g4*4 + r;
            bool valid = (s1row < SS);
            if (job == 3)  valid = valid && (s1row == 48);
            if (job == 19) valid = valid && (s1row >= 49);
            if (valid) {
                const int i = s1row / 49, p = s1row - i*49;
                const size_t rb = ((size_t)((b*LL + i)*NWIN + nwin)*PP + p)*DIMM + m*CHN;
                o_pre[rb + c16]      = bfbits(out0[r]);
                o_pre[rb + 16 + c16] = bfbits(out1[r]);
            }
        }
    }
}

// ---------------- kernel 3: out = o_pre @ Wo^T via MFMA, de-staged ----------------
__global__ __launch_bounds__(256) void k_out2(
    const u16* __restrict__ pre, const u16* __restrict__ Wob,
    float* __restrict__ out)
{
    const int tid = threadIdx.x;
    const int w = tid >> 6, lane = tid & 63;
    const int g4 = lane >> 4, c16 = lane & 15;
    const int bid = blockIdx.x;
    const u16* ps = pre + (size_t)bid * (PP*DIMM);

    int rowc[4];
    #pragma unroll
    for (int mm = 0; mm < 4; ++mm) {
        const int r0 = mm*16 + c16;
        rowc[mm] = (r0 < PP) ? r0 : (PP - 1);
    }

    const f32x4 zero4 = {0.f, 0.f, 0.f, 0.f};
    f32x4 acc[4][4];
    #pragma unroll
    for (int mm = 0; mm < 4; ++mm)
        #pragma unroll
        for (int nn = 0; nn < 4; ++nn) acc[mm][nn] = zero4;

    for (int ks = 0; ks < 8; ++ks) {
        bf16x8 a[4], bb[4];
        #pragma unroll
        for (int mm = 0; mm < 4; ++mm)
            a[mm] = *(const bf16x8*)(ps + (size_t)rowc[mm]*DIMM + ks*32 + g4*8);
        #pragma unroll
        for (int nn = 0; nn < 4; ++nn)
            bb[nn] = *(const bf16x8*)&Wob[(size_t)(w*64 + nn*16 + c16)*256 + ks*32 + g4*8];
        #pragma unroll
        for (int mm = 0; mm < 4; ++mm)
            #pragma unroll
            for (int nn = 0; nn < 4; ++nn)
                acc[mm][nn] = mfma16(a[mm], bb[nn], acc[mm][nn]);
    }

    float* op = out + (size_t)bid * (PP*DIMM);
    #pragma unroll
    for (int nn = 0; nn < 4; ++nn) {
        const int col = w*64 + nn*16 + c16;
        #pragma unroll
        for (int mm = 0; mm < 4; ++mm) {
            #pragma unroll
            for (int r = 0; r < 4; ++r) {
                const int row = mm*16 + g4*4 + r;
                if (row < PP) op[(size_t)row*DIMM + col] = acc[mm][nn][r];
            }
        }
    }
}

extern "C" void kernel_launch(void* const* d_in, const int* in_sizes, int n_in,
                              void* d_out, int out_size, void* d_ws, size_t ws_size,
                              hipStream_t stream)
{
    (void)in_sizes; (void)n_in; (void)out_size; (void)ws_size;
    const float* x        = (const float*)d_in[0];
    const float* Wq       = (const float*)d_in[1];
    const float* bq       = (const float*)d_in[2];
    const float* Wk       = (const float*)d_in[3];
    const float* bk       = (const float*)d_in[4];
    const float* Wv       = (const float*)d_in[5];
    const float* bv       = (const float*)d_in[6];
    const float* rel_att  = (const float*)d_in[7];
    const float* rel_msg  = (const float*)d_in[8];
    const float* bias_tab = (const float*)d_in[9];
    const float* Wo       = (const float*)d_in[10];
    const int*   atype    = (const int*)d_in[11];
    float* out = (float*)d_out;

    // workspace layout (bytes):
    //  wT    bf16: [0, 786432)
    //  Wob   bf16: [786432, 917504)
    //  raT   bf16: [917504, 983040)
    //  rmb   bf16: [983040, 1048576)
    //  biasM f32 : [1048576, 3908608)
    //  qb, kb, vb bf16: 3 x 19267584
    //  o_preb bf16: [61711360, 80978944)
    //  xb bf16 (25.2 MB): [61711360, 86877184)  ALIASES o_preb - xb is dead
    //    before k_attn writes o_pre (prep->qkv2 read xb; attn->out2 use o_preb).
    //  peak 86,877,184 B <= 96,600,064 proven available (R1).
    char* ws = (char*)d_ws;
    u16* wT     = (u16*)ws;
    u16* Wob    = (u16*)(ws + 786432);
    u16* raT    = (u16*)(ws + 917504);
    u16* rmb    = (u16*)(ws + 983040);
    float* biasM= (float*)(ws + 1048576);
    u16* qb     = (u16*)(ws + 3908608);
    u16* kb     = (u16*)(ws + 3908608 + 1ull*19267584);
    u16* vb     = (u16*)(ws + 3908608 + 2ull*19267584);
    u16* o_preb = (u16*)(ws + 61711360);
    u16* xb     = (u16*)(ws + 61711360);

    k_prep<<<9705, 256, 0, stream>>>(Wq, Wk, Wv, Wo, rel_att, rel_msg, bias_tab, x,
                                     wT, Wob, raT, rmb, biasM, xb);
    k_qkv2<<<3*BB*LL*NWIN, 256, 0, stream>>>(xb, wT, bq, bk, bv, atype, qb, kb, vb);
    k_attn<<<BB*NWIN*HEADS, 256, 0, stream>>>(qb, kb, vb, raT, rmb, biasM, atype, o_preb);
    k_out2<<<BB*LL*NWIN, 256, 0, stream>>>(o_preb, Wob, out);
}